// Round 1
// baseline (790.569 us; speedup 1.0000x reference)
//
#include <hip/hip_runtime.h>
#include <math.h>

#define NN 50000
#define NE 800000
#define NEG 0.2f

__device__ __forceinline__ float lrelu(float x){ return x > 0.f ? x : NEG * x; }

// ---------- CSR build ----------
__global__ void k_hist(const int* __restrict__ dst, int* __restrict__ deg, int e){
    int i = blockIdx.x * blockDim.x + threadIdx.x;
    if (i < e) atomicAdd(&deg[dst[i]], 1);
}

__global__ __launch_bounds__(1024) void k_scan(const int* __restrict__ deg,
                                               int* __restrict__ rowstart,
                                               int* __restrict__ cursor, int n){
    __shared__ int swave[16];
    int tid = threadIdx.x, lane = tid & 63, wid = tid >> 6;
    int carry = 0;
    for (int base = 0; base < n; base += 1024){
        int i = base + tid;
        int v = (i < n) ? deg[i] : 0;
        int incl = v;
        #pragma unroll
        for (int off = 1; off < 64; off <<= 1){
            int t = __shfl_up(incl, off);
            if (lane >= off) incl += t;
        }
        if (lane == 63) swave[wid] = incl;
        __syncthreads();
        if (wid == 0){
            int sv = (lane < 16) ? swave[lane] : 0;
            #pragma unroll
            for (int off = 1; off < 16; off <<= 1){
                int t = __shfl_up(sv, off);
                if (lane >= off) sv += t;
            }
            if (lane < 16) swave[lane] = sv;
        }
        __syncthreads();
        int woff = wid ? swave[wid - 1] : 0;
        int exc = carry + woff + incl - v;
        if (i < n){ rowstart[i] = exc; cursor[i] = exc; }
        carry += swave[15];
        __syncthreads();
    }
    if (tid == 0) rowstart[n] = carry;
}

__global__ void k_scatter(const int* __restrict__ src, const int* __restrict__ dst,
                          int* __restrict__ cursor, int* __restrict__ csr, int e){
    int i = blockIdx.x * blockDim.x + threadIdx.x;
    if (i < e){
        int p = atomicAdd(&cursor[dst[i]], 1);
        csr[p] = src[i];
    }
}

// ---------- linear (64x64) + attention projections, one wave per node ----------
__global__ __launch_bounds__(256) void k_lin_att(const float* __restrict__ X,
                                                 const float* __restrict__ W,
                                                 const float* __restrict__ b,
                                                 const float* __restrict__ att,
                                                 float* __restrict__ H,
                                                 float* __restrict__ ad,
                                                 float* __restrict__ as_, int n){
    __shared__ float Wt[64 * 64];
    __shared__ float bsh[64];
    __shared__ float atsh[128];
    int tid = threadIdx.x;
    for (int i = tid; i < 4096; i += 256){
        int f = i >> 6, k = i & 63;
        Wt[k * 64 + f] = W[i];                 // store transposed: Wt[k][f]
    }
    if (tid < 64) bsh[tid] = b[tid];
    if (tid < 128) atsh[tid] = att[tid];
    __syncthreads();

    int lane = tid & 63, wid = tid >> 6;
    int node = blockIdx.x * 4 + wid;
    if (node >= n) return;

    float xv = X[node * 64 + lane];
    float acc = bsh[lane];
    #pragma unroll
    for (int k = 0; k < 64; ++k)
        acc = fmaf(__shfl(xv, k), Wt[k * 64 + lane], acc);
    H[node * 64 + lane] = acc;

    float pd = atsh[lane] * acc;
    float ps = atsh[64 + lane] * acc;
    #pragma unroll
    for (int off = 32; off; off >>= 1){
        pd += __shfl_xor(pd, off);
        ps += __shfl_xor(ps, off);
    }
    if (lane == 0){ ad[node] = pd; as_[node] = ps; }
}

// ---------- GAT aggregation (softmax over incoming edges), one wave per node ----------
__global__ __launch_bounds__(256) void k_agg(const float* __restrict__ H,
                                             const float* __restrict__ ad,
                                             const float* __restrict__ as_,
                                             const int* __restrict__ rowstart,
                                             const int* __restrict__ csr,
                                             const float* __restrict__ bias,
                                             float* __restrict__ OUT, int n){
    int tid = threadIdx.x, lane = tid & 63, wid = tid >> 6;
    int node = blockIdx.x * 4 + wid;
    if (node >= n) return;
    int beg = rowstart[node], end = rowstart[node + 1];
    float adn = ad[node];

    float m = -INFINITY;
    for (int k = beg + lane; k < end; k += 64)
        m = fmaxf(m, lrelu(adn + as_[csr[k]]));
    #pragma unroll
    for (int off = 32; off; off >>= 1) m = fmaxf(m, __shfl_xor(m, off));

    float acc = 0.f, denom = 0.f;
    for (int k = beg; k < end; ++k){
        int s = csr[k];
        float e = __expf(lrelu(adn + as_[s]) - m);
        denom += e;
        acc = fmaf(e, H[s * 64 + lane], acc);
    }
    float o = acc / (denom + 1e-16f) + bias[lane];
    OUT[node * 64 + lane] = fmaxf(o, 0.f);   // relu follows both GAT layers
}

// ---------- MLP (64->64->40) + log_softmax, one wave per node ----------
__global__ __launch_bounds__(256) void k_mlp(const float* __restrict__ G,
                                             const float* __restrict__ W1,
                                             const float* __restrict__ b1,
                                             const float* __restrict__ W2,
                                             const float* __restrict__ b2,
                                             float* __restrict__ out, int n){
    __shared__ float Wt1[64 * 64];
    __shared__ float Wt2[64 * 40];
    __shared__ float b1s[64], b2s[40];
    int tid = threadIdx.x;
    for (int i = tid; i < 4096; i += 256){
        int f = i >> 6, k = i & 63;
        Wt1[k * 64 + f] = W1[i];
    }
    for (int i = tid; i < 2560; i += 256){
        int c = i / 64, k = i % 64;
        Wt2[k * 40 + c] = W2[i];
    }
    if (tid < 64) b1s[tid] = b1[tid];
    if (tid < 40) b2s[tid] = b2[tid];
    __syncthreads();

    int lane = tid & 63, wid = tid >> 6;
    int node = blockIdx.x * 4 + wid;
    if (node >= n) return;

    float g = G[node * 64 + lane];
    float t = b1s[lane];
    #pragma unroll
    for (int k = 0; k < 64; ++k)
        t = fmaf(__shfl(g, k), Wt1[k * 64 + lane], t);

    float l = (lane < 40) ? b2s[lane] : -INFINITY;
    #pragma unroll
    for (int k = 0; k < 64; ++k){
        float tv = __shfl(t, k);
        if (lane < 40) l = fmaf(tv, Wt2[k * 40 + lane], l);
    }

    float m = l;
    #pragma unroll
    for (int off = 32; off; off >>= 1) m = fmaxf(m, __shfl_xor(m, off));
    float e = (lane < 40) ? __expf(l - m) : 0.f;
    float s = e;
    #pragma unroll
    for (int off = 32; off; off >>= 1) s += __shfl_xor(s, off);
    float lse = m + __logf(s);
    if (lane < 40) out[node * 40 + lane] = l - lse;
}

extern "C" void kernel_launch(void* const* d_in, const int* in_sizes, int n_in,
                              void* d_out, int out_size, void* d_ws, size_t ws_size,
                              hipStream_t stream){
    const float* x     = (const float*)d_in[0];
    const int*   ei    = (const int*)  d_in[1];
    const float* W1    = (const float*)d_in[2];
    const float* b1    = (const float*)d_in[3];
    const float* att1  = (const float*)d_in[4];
    const float* bias1 = (const float*)d_in[5];
    const float* W2    = (const float*)d_in[6];
    const float* b2    = (const float*)d_in[7];
    const float* att2  = (const float*)d_in[8];
    const float* bias2 = (const float*)d_in[9];
    const float* Wp1   = (const float*)d_in[10];
    const float* bp1   = (const float*)d_in[11];
    const float* Wp2   = (const float*)d_in[12];
    const float* bp2   = (const float*)d_in[13];
    float* out = (float*)d_out;

    // workspace carve (~30 MB)
    float* h   = (float*)d_ws;             // [NN*64]
    float* g   = h + (size_t)NN * 64;      // [NN*64]
    float* ad  = g + (size_t)NN * 64;      // [NN]
    float* as_ = ad + NN;                  // [NN]
    int* deg      = (int*)(as_ + NN);      // [NN]
    int* rowstart = deg + NN;              // [NN+1]
    int* cursor   = rowstart + NN + 8;     // [NN]
    int* csr      = cursor + NN;           // [NE]

    const int* srcv = ei;
    const int* dstv = ei + NE;

    hipMemsetAsync(deg, 0, NN * sizeof(int), stream);
    int eb = (NE + 255) / 256;
    k_hist   <<<eb, 256, 0, stream>>>(dstv, deg, NE);
    k_scan   <<<1, 1024, 0, stream>>>(deg, rowstart, cursor, NN);
    k_scatter<<<eb, 256, 0, stream>>>(srcv, dstv, cursor, csr, NE);

    int nb = (NN + 3) / 4;
    k_lin_att<<<nb, 256, 0, stream>>>(x, W1, b1, att1, h, ad, as_, NN);
    k_agg    <<<nb, 256, 0, stream>>>(h, ad, as_, rowstart, csr, bias1, g, NN);
    k_lin_att<<<nb, 256, 0, stream>>>(g, W2, b2, att2, h, ad, as_, NN);
    k_agg    <<<nb, 256, 0, stream>>>(h, ad, as_, rowstart, csr, bias2, g, NN);
    k_mlp    <<<nb, 256, 0, stream>>>(g, Wp1, bp1, Wp2, bp2, out, NN);
}

// Round 2
// 346.005 us; speedup vs baseline: 2.2848x; 2.2848x over previous
//
#include <hip/hip_runtime.h>
#include <math.h>

#define NN 50000
#define NE 800000
#define NEG 0.2f

__device__ __forceinline__ float lrelu(float x){ return x > 0.f ? x : NEG * x; }

__device__ __forceinline__ float bcastf(float v, int l){
    return __uint_as_float(__builtin_amdgcn_readlane(__float_as_uint(v), l));
}
__device__ __forceinline__ int bcasti(int v, int l){
    return (int)__builtin_amdgcn_readlane((unsigned)v, l);
}

// ---------- CSR build ----------
__global__ void k_hist(const int* __restrict__ dst, int* __restrict__ deg, int e){
    int i = blockIdx.x * blockDim.x + threadIdx.x;
    if (i < e) atomicAdd(&deg[dst[i]], 1);
}

__global__ __launch_bounds__(1024) void k_scan(const int* __restrict__ deg,
                                               int* __restrict__ rowstart,
                                               int* __restrict__ cursor, int n){
    __shared__ int swave[16];
    int tid = threadIdx.x, lane = tid & 63, wid = tid >> 6;
    int carry = 0;
    for (int base = 0; base < n; base += 1024){
        int i = base + tid;
        int v = (i < n) ? deg[i] : 0;
        int incl = v;
        #pragma unroll
        for (int off = 1; off < 64; off <<= 1){
            int t = __shfl_up(incl, off);
            if (lane >= off) incl += t;
        }
        if (lane == 63) swave[wid] = incl;
        __syncthreads();
        if (wid == 0){
            int sv = (lane < 16) ? swave[lane] : 0;
            #pragma unroll
            for (int off = 1; off < 16; off <<= 1){
                int t = __shfl_up(sv, off);
                if (lane >= off) sv += t;
            }
            if (lane < 16) swave[lane] = sv;
        }
        __syncthreads();
        int woff = wid ? swave[wid - 1] : 0;
        int exc = carry + woff + incl - v;
        if (i < n){ rowstart[i] = exc; cursor[i] = exc; }
        carry += swave[15];
        __syncthreads();
    }
    if (tid == 0) rowstart[n] = carry;
}

__global__ void k_scatter(const int* __restrict__ src, const int* __restrict__ dst,
                          int* __restrict__ cursor, int* __restrict__ csr, int e){
    int i = blockIdx.x * blockDim.x + threadIdx.x;
    if (i < e){
        int p = atomicAdd(&cursor[dst[i]], 1);
        csr[p] = src[i];
    }
}

// ---------- linear (64x64) + attention projections, one wave per node ----------
// LDS stride padded to 65: store bank=(k+f)%32, read bank=(k+lane)%32 -> conflict-free
__global__ __launch_bounds__(256) void k_lin_att(const float* __restrict__ X,
                                                 const float* __restrict__ W,
                                                 const float* __restrict__ b,
                                                 const float* __restrict__ att,
                                                 float* __restrict__ H,
                                                 float* __restrict__ ad,
                                                 float* __restrict__ as_, int n){
    __shared__ float Wt[64 * 65];
    __shared__ float bsh[64];
    __shared__ float atsh[128];
    int tid = threadIdx.x;
    for (int i = tid; i < 4096; i += 256){
        int f = i >> 6, k = i & 63;
        Wt[k * 65 + f] = W[i];                 // transposed: Wt[k][f], stride 65
    }
    if (tid < 64) bsh[tid] = b[tid];
    if (tid < 128) atsh[tid] = att[tid];
    __syncthreads();

    int lane = tid & 63, wid = tid >> 6;
    int node = blockIdx.x * 4 + wid;
    if (node >= n) return;

    float xv = X[node * 64 + lane];
    float acc = bsh[lane];
    #pragma unroll
    for (int k = 0; k < 64; ++k)
        acc = fmaf(bcastf(xv, k), Wt[k * 65 + lane], acc);
    H[node * 64 + lane] = acc;

    float pd = atsh[lane] * acc;
    float ps = atsh[64 + lane] * acc;
    #pragma unroll
    for (int off = 32; off; off >>= 1){
        pd += __shfl_xor(pd, off);
        ps += __shfl_xor(ps, off);
    }
    if (lane == 0){ ad[node] = pd; as_[node] = ps; }
}

// ---------- GAT aggregation (softmax over incoming edges), one wave per node ----------
// pass 1: lane-parallel edge logits (cached for first chunk of 64)
// pass 2: independent H-row gathers, unrolled x4 so loads overlap
__global__ __launch_bounds__(256) void k_agg(const float* __restrict__ H,
                                             const float* __restrict__ ad,
                                             const float* __restrict__ as_,
                                             const int* __restrict__ rowstart,
                                             const int* __restrict__ csr,
                                             const float* __restrict__ bias,
                                             float* __restrict__ OUT, int n){
    int tid = threadIdx.x, lane = tid & 63, wid = tid >> 6;
    int node = blockIdx.x * 4 + wid;
    if (node >= n) return;
    int beg = rowstart[node], end = rowstart[node + 1];
    float adn = ad[node];

    // chunk-0 edge (cached in registers)
    int k0 = beg + lane;
    int s0 = (k0 < end) ? csr[k0] : 0;
    float a0 = (k0 < end) ? lrelu(adn + as_[s0]) : -INFINITY;

    // global max over all edges
    float m = a0;
    for (int k = beg + 64 + lane; k < end; k += 64)
        m = fmaxf(m, lrelu(adn + as_[csr[k]]));
    #pragma unroll
    for (int off = 32; off; off >>= 1) m = fmaxf(m, __shfl_xor(m, off));

    float acc = 0.f, denom = 0.f;

    // chunk 0 from cache
    {
        float e = (k0 < end) ? __expf(a0 - m) : 0.f;
        float es = e;
        #pragma unroll
        for (int off = 32; off; off >>= 1) es += __shfl_xor(es, off);
        denom += es;
        int cnt = min(64, end - beg);
        int j = 0;
        for (; j + 4 <= cnt; j += 4){
            int   sa = bcasti(s0, j),     sb = bcasti(s0, j + 1);
            int   sc = bcasti(s0, j + 2), sd = bcasti(s0, j + 3);
            float ea = bcastf(e, j),      eb = bcastf(e, j + 1);
            float ec = bcastf(e, j + 2),  ed = bcastf(e, j + 3);
            float ha = H[(size_t)sa * 64 + lane];
            float hb = H[(size_t)sb * 64 + lane];
            float hc = H[(size_t)sc * 64 + lane];
            float hd = H[(size_t)sd * 64 + lane];
            acc = fmaf(ea, ha, acc);
            acc = fmaf(eb, hb, acc);
            acc = fmaf(ec, hc, acc);
            acc = fmaf(ed, hd, acc);
        }
        for (; j < cnt; ++j){
            int   sj = bcasti(s0, j);
            float ej = bcastf(e, j);
            acc = fmaf(ej, H[(size_t)sj * 64 + lane], acc);
        }
    }

    // rare extra chunks (deg > 64)
    for (int cbeg = beg + 64; cbeg < end; cbeg += 64){
        int k = cbeg + lane;
        int s = (k < end) ? csr[k] : 0;
        float e = (k < end) ? __expf(lrelu(adn + as_[s]) - m) : 0.f;
        float es = e;
        #pragma unroll
        for (int off = 32; off; off >>= 1) es += __shfl_xor(es, off);
        denom += es;
        int cnt = min(64, end - cbeg);
        for (int j = 0; j < cnt; ++j){
            int   sj = bcasti(s, j);
            float ej = bcastf(e, j);
            acc = fmaf(ej, H[(size_t)sj * 64 + lane], acc);
        }
    }

    float o = acc / (denom + 1e-16f) + bias[lane];
    OUT[node * 64 + lane] = fmaxf(o, 0.f);   // relu follows both GAT layers
}

// ---------- MLP (64->64->40) + log_softmax, one wave per node ----------
__global__ __launch_bounds__(256) void k_mlp(const float* __restrict__ G,
                                             const float* __restrict__ W1,
                                             const float* __restrict__ b1,
                                             const float* __restrict__ W2,
                                             const float* __restrict__ b2,
                                             float* __restrict__ out, int n){
    __shared__ float Wt1[64 * 65];
    __shared__ float Wt2[64 * 41];
    __shared__ float b1s[64], b2s[40];
    int tid = threadIdx.x;
    for (int i = tid; i < 4096; i += 256){
        int f = i >> 6, k = i & 63;
        Wt1[k * 65 + f] = W1[i];
    }
    for (int i = tid; i < 2560; i += 256){
        int c = i / 64, k = i % 64;
        Wt2[k * 41 + c] = W2[i];
    }
    if (tid < 64) b1s[tid] = b1[tid];
    if (tid < 40) b2s[tid] = b2[tid];
    __syncthreads();

    int lane = tid & 63, wid = tid >> 6;
    int node = blockIdx.x * 4 + wid;
    if (node >= n) return;

    float g = G[node * 64 + lane];
    float t = b1s[lane];
    #pragma unroll
    for (int k = 0; k < 64; ++k)
        t = fmaf(bcastf(g, k), Wt1[k * 65 + lane], t);

    float l = (lane < 40) ? b2s[lane] : -INFINITY;
    #pragma unroll
    for (int k = 0; k < 64; ++k){
        float tv = bcastf(t, k);
        if (lane < 40) l = fmaf(tv, Wt2[k * 41 + lane], l);
    }

    float m = l;
    #pragma unroll
    for (int off = 32; off; off >>= 1) m = fmaxf(m, __shfl_xor(m, off));
    float e = (lane < 40) ? __expf(l - m) : 0.f;
    float s = e;
    #pragma unroll
    for (int off = 32; off; off >>= 1) s += __shfl_xor(s, off);
    float lse = m + __logf(s);
    if (lane < 40) out[node * 40 + lane] = l - lse;
}

extern "C" void kernel_launch(void* const* d_in, const int* in_sizes, int n_in,
                              void* d_out, int out_size, void* d_ws, size_t ws_size,
                              hipStream_t stream){
    const float* x     = (const float*)d_in[0];
    const int*   ei    = (const int*)  d_in[1];
    const float* W1    = (const float*)d_in[2];
    const float* b1    = (const float*)d_in[3];
    const float* att1  = (const float*)d_in[4];
    const float* bias1 = (const float*)d_in[5];
    const float* W2    = (const float*)d_in[6];
    const float* b2    = (const float*)d_in[7];
    const float* att2  = (const float*)d_in[8];
    const float* bias2 = (const float*)d_in[9];
    const float* Wp1   = (const float*)d_in[10];
    const float* bp1   = (const float*)d_in[11];
    const float* Wp2   = (const float*)d_in[12];
    const float* bp2   = (const float*)d_in[13];
    float* out = (float*)d_out;

    // workspace carve (~30 MB)
    float* h   = (float*)d_ws;             // [NN*64]
    float* g   = h + (size_t)NN * 64;      // [NN*64]
    float* ad  = g + (size_t)NN * 64;      // [NN]
    float* as_ = ad + NN;                  // [NN]
    int* deg      = (int*)(as_ + NN);      // [NN]
    int* rowstart = deg + NN;              // [NN+1]
    int* cursor   = rowstart + NN + 8;     // [NN]
    int* csr      = cursor + NN;           // [NE]

    const int* srcv = ei;
    const int* dstv = ei + NE;

    hipMemsetAsync(deg, 0, NN * sizeof(int), stream);
    int eb = (NE + 255) / 256;
    k_hist   <<<eb, 256, 0, stream>>>(dstv, deg, NE);
    k_scan   <<<1, 1024, 0, stream>>>(deg, rowstart, cursor, NN);
    k_scatter<<<eb, 256, 0, stream>>>(srcv, dstv, cursor, csr, NE);

    int nb = (NN + 3) / 4;
    k_lin_att<<<nb, 256, 0, stream>>>(x, W1, b1, att1, h, ad, as_, NN);
    k_agg    <<<nb, 256, 0, stream>>>(h, ad, as_, rowstart, csr, bias1, g, NN);
    k_lin_att<<<nb, 256, 0, stream>>>(g, W2, b2, att2, h, ad, as_, NN);
    k_agg    <<<nb, 256, 0, stream>>>(h, ad, as_, rowstart, csr, bias2, g, NN);
    k_mlp    <<<nb, 256, 0, stream>>>(g, Wp1, bp1, Wp2, bp2, out, NN);
}

// Round 3
// 256.793 us; speedup vs baseline: 3.0786x; 1.3474x over previous
//
#include <hip/hip_runtime.h>
#include <math.h>

#define NN 50000
#define NE 800000
#define NEG 0.2f

typedef __attribute__((ext_vector_type(8))) short short8v;  // 8 bf16 (4 VGPRs)
typedef __attribute__((ext_vector_type(4))) float f32x4;    // MFMA C/D frag

__device__ __forceinline__ float lrelu(float x){ return x > 0.f ? x : NEG * x; }

__device__ __forceinline__ float bcastf(float v, int l){
    return __uint_as_float(__builtin_amdgcn_readlane(__float_as_uint(v), l));
}
__device__ __forceinline__ int bcasti(int v, int l){
    return (int)__builtin_amdgcn_readlane((unsigned)v, l);
}
__device__ __forceinline__ short bf16t(float x){ return (short)(__float_as_uint(x) >> 16); }
__device__ __forceinline__ float bf16tof(short s){
    return __uint_as_float(((unsigned)(unsigned short)s) << 16);
}

// ---------- CSR build ----------
__global__ void k_hist(const int* __restrict__ dst, int* __restrict__ deg, int e){
    int i = blockIdx.x * blockDim.x + threadIdx.x;
    if (i < e) atomicAdd(&deg[dst[i]], 1);
}

__global__ __launch_bounds__(1024) void k_scan(const int* __restrict__ deg,
                                               int* __restrict__ rowstart,
                                               int* __restrict__ cursor, int n){
    __shared__ int swave[16];
    int tid = threadIdx.x, lane = tid & 63, wid = tid >> 6;
    int carry = 0;
    for (int base = 0; base < n; base += 1024){
        int i = base + tid;
        int v = (i < n) ? deg[i] : 0;
        int incl = v;
        #pragma unroll
        for (int off = 1; off < 64; off <<= 1){
            int t = __shfl_up(incl, off);
            if (lane >= off) incl += t;
        }
        if (lane == 63) swave[wid] = incl;
        __syncthreads();
        if (wid == 0){
            int sv = (lane < 16) ? swave[lane] : 0;
            #pragma unroll
            for (int off = 1; off < 16; off <<= 1){
                int t = __shfl_up(sv, off);
                if (lane >= off) sv += t;
            }
            if (lane < 16) swave[lane] = sv;
        }
        __syncthreads();
        int woff = wid ? swave[wid - 1] : 0;
        int exc = carry + woff + incl - v;
        if (i < n){ rowstart[i] = exc; cursor[i] = exc; }
        carry += swave[15];
        __syncthreads();
    }
    if (tid == 0) rowstart[n] = carry;
}

__global__ void k_scatter(const int* __restrict__ src, const int* __restrict__ dst,
                          int* __restrict__ cursor, int* __restrict__ csr, int e){
    int i = blockIdx.x * blockDim.x + threadIdx.x;
    if (i < e){
        int p = atomicAdd(&cursor[dst[i]], 1);
        csr[p] = src[i];
    }
}

// ---------- MFMA linear: H = X@W^T + b, plus attention scalars ----------
// One wave = 16 nodes x 64 features. Split-bf16 3-term for fp32 accuracy.
// A frag: lane holds X[nb + (l&15)][ks*32 + (l>>4)*8 + j], j=0..7
// B frag: lane holds W[nt*16 + (l&15)][ks*32 + (l>>4)*8 + j]   (B = W^T, K x N)
// C/D: col(=feature within tile) = l&15, row(=node within 16) = (l>>4)*4 + reg
__global__ __launch_bounds__(256) void k_lin_mfma(const float* __restrict__ X,
                                                  const float* __restrict__ W,
                                                  const float* __restrict__ b,
                                                  const float* __restrict__ att,
                                                  float* __restrict__ H,
                                                  float* __restrict__ ad,
                                                  float* __restrict__ as_, int n){
    int lane = threadIdx.x & 63, wid = threadIdx.x >> 6;
    int nb = blockIdx.x * 64 + wid * 16;
    if (nb >= n) return;
    int r0 = lane & 15, rg = lane >> 4;

    // A fragments (hi/lo split)
    short8v a_hi[2], a_lo[2];
    int arow = nb + r0; if (arow >= n) arow = n - 1;
    const float* xp = X + (size_t)arow * 64 + rg * 8;
    #pragma unroll
    for (int ks = 0; ks < 2; ++ks){
        #pragma unroll
        for (int j = 0; j < 8; ++j){
            float v = xp[ks * 32 + j];
            short h = bf16t(v);
            a_hi[ks][j] = h;
            a_lo[ks][j] = bf16t(v - bf16tof(h));
        }
    }

    f32x4 acc[4] = {{0,0,0,0},{0,0,0,0},{0,0,0,0},{0,0,0,0}};
    #pragma unroll
    for (int nt = 0; nt < 4; ++nt){
        const float* wp = W + (size_t)(nt * 16 + r0) * 64 + rg * 8;
        #pragma unroll
        for (int ks = 0; ks < 2; ++ks){
            short8v b_hi, b_lo;
            #pragma unroll
            for (int j = 0; j < 8; ++j){
                float v = wp[ks * 32 + j];
                short h = bf16t(v);
                b_hi[j] = h;
                b_lo[j] = bf16t(v - bf16tof(h));
            }
            acc[nt] = __builtin_amdgcn_mfma_f32_16x16x32_bf16(a_hi[ks], b_hi, acc[nt], 0, 0, 0);
            acc[nt] = __builtin_amdgcn_mfma_f32_16x16x32_bf16(a_hi[ks], b_lo, acc[nt], 0, 0, 0);
            acc[nt] = __builtin_amdgcn_mfma_f32_16x16x32_bf16(a_lo[ks], b_hi, acc[nt], 0, 0, 0);
        }
    }

    // bias + store H (keep values in acc for the attention dots)
    #pragma unroll
    for (int nt = 0; nt < 4; ++nt){
        float bb = b[nt * 16 + r0];
        #pragma unroll
        for (int q = 0; q < 4; ++q){
            int node = nb + rg * 4 + q;
            float v = acc[nt][q] + bb;
            acc[nt][q] = v;
            if (node < n) H[(size_t)node * 64 + nt * 16 + r0] = v;
        }
    }

    // attention projections: ad = h . att[0:64], as = h . att[64:128]
    float attd[4], atts[4];
    #pragma unroll
    for (int nt = 0; nt < 4; ++nt){
        attd[nt] = att[nt * 16 + r0];
        atts[nt] = att[64 + nt * 16 + r0];
    }
    #pragma unroll
    for (int q = 0; q < 4; ++q){
        float pd = 0.f, ps = 0.f;
        #pragma unroll
        for (int nt = 0; nt < 4; ++nt){
            pd = fmaf(attd[nt], acc[nt][q], pd);
            ps = fmaf(atts[nt], acc[nt][q], ps);
        }
        #pragma unroll
        for (int off = 8; off; off >>= 1){
            pd += __shfl_xor(pd, off);
            ps += __shfl_xor(ps, off);
        }
        int node = nb + rg * 4 + q;
        if (r0 == 0 && node < n){ ad[node] = pd; as_[node] = ps; }
    }
}

// ---------- GAT aggregation (softmax over incoming edges), one wave per node ----------
__global__ __launch_bounds__(256) void k_agg(const float* __restrict__ H,
                                             const float* __restrict__ ad,
                                             const float* __restrict__ as_,
                                             const int* __restrict__ rowstart,
                                             const int* __restrict__ csr,
                                             const float* __restrict__ bias,
                                             float* __restrict__ OUT, int n){
    int tid = threadIdx.x, lane = tid & 63, wid = tid >> 6;
    int node = blockIdx.x * 4 + wid;
    if (node >= n) return;
    int beg = rowstart[node], end = rowstart[node + 1];
    float adn = ad[node];

    int k0 = beg + lane;
    int s0 = (k0 < end) ? csr[k0] : 0;
    float a0 = (k0 < end) ? lrelu(adn + as_[s0]) : -INFINITY;

    float m = a0;
    for (int k = beg + 64 + lane; k < end; k += 64)
        m = fmaxf(m, lrelu(adn + as_[csr[k]]));
    #pragma unroll
    for (int off = 32; off; off >>= 1) m = fmaxf(m, __shfl_xor(m, off));

    float acc = 0.f, denom = 0.f;
    {
        float e = (k0 < end) ? __expf(a0 - m) : 0.f;
        float es = e;
        #pragma unroll
        for (int off = 32; off; off >>= 1) es += __shfl_xor(es, off);
        denom += es;
        int cnt = min(64, end - beg);
        int j = 0;
        for (; j + 4 <= cnt; j += 4){
            int   sa = bcasti(s0, j),     sb = bcasti(s0, j + 1);
            int   sc = bcasti(s0, j + 2), sd = bcasti(s0, j + 3);
            float ea = bcastf(e, j),      eb = bcastf(e, j + 1);
            float ec = bcastf(e, j + 2),  ed = bcastf(e, j + 3);
            float ha = H[(size_t)sa * 64 + lane];
            float hb = H[(size_t)sb * 64 + lane];
            float hc = H[(size_t)sc * 64 + lane];
            float hd = H[(size_t)sd * 64 + lane];
            acc = fmaf(ea, ha, acc);
            acc = fmaf(eb, hb, acc);
            acc = fmaf(ec, hc, acc);
            acc = fmaf(ed, hd, acc);
        }
        for (; j < cnt; ++j){
            int   sj = bcasti(s0, j);
            float ej = bcastf(e, j);
            acc = fmaf(ej, H[(size_t)sj * 64 + lane], acc);
        }
    }
    for (int cbeg = beg + 64; cbeg < end; cbeg += 64){
        int k = cbeg + lane;
        int s = (k < end) ? csr[k] : 0;
        float e = (k < end) ? __expf(lrelu(adn + as_[s]) - m) : 0.f;
        float es = e;
        #pragma unroll
        for (int off = 32; off; off >>= 1) es += __shfl_xor(es, off);
        denom += es;
        int cnt = min(64, end - cbeg);
        for (int j = 0; j < cnt; ++j){
            int   sj = bcasti(s, j);
            float ej = bcastf(e, j);
            acc = fmaf(ej, H[(size_t)sj * 64 + lane], acc);
        }
    }

    float o = acc / (denom + 1e-16f) + bias[lane];
    OUT[node * 64 + lane] = fmaxf(o, 0.f);
}

// ---------- collapse MLP: Wc = Wp2@Wp1 [40x64], bc = Wp2@bp1 + bp2 [40] ----------
__global__ void k_wcomb(const float* __restrict__ Wp1, const float* __restrict__ bp1,
                        const float* __restrict__ Wp2, const float* __restrict__ bp2,
                        float* __restrict__ Wc, float* __restrict__ bc){
    int idx = blockIdx.x * 256 + threadIdx.x;
    if (idx < 40 * 64){
        int c = idx >> 6, k = idx & 63;
        float s = 0.f;
        #pragma unroll 8
        for (int j = 0; j < 64; ++j) s = fmaf(Wp2[c * 64 + j], Wp1[j * 64 + k], s);
        Wc[idx] = s;
    }
    if (idx < 40){
        float s = bp2[idx];
        for (int j = 0; j < 64; ++j) s = fmaf(Wp2[idx * 64 + j], bp1[j], s);
        bc[idx] = s;
    }
}

// ---------- MFMA MLP: out = log_softmax(G@Wc^T + bc) ----------
__global__ __launch_bounds__(256) void k_mlp_mfma(const float* __restrict__ G,
                                                  const float* __restrict__ Wc,
                                                  const float* __restrict__ bc,
                                                  float* __restrict__ out, int n){
    int lane = threadIdx.x & 63, wid = threadIdx.x >> 6;
    int nb = blockIdx.x * 64 + wid * 16;
    if (nb >= n) return;
    int r0 = lane & 15, rg = lane >> 4;

    short8v a_hi[2], a_lo[2];
    int arow = nb + r0; if (arow >= n) arow = n - 1;
    const float* gp = G + (size_t)arow * 64 + rg * 8;
    #pragma unroll
    for (int ks = 0; ks < 2; ++ks){
        #pragma unroll
        for (int j = 0; j < 8; ++j){
            float v = gp[ks * 32 + j];
            short h = bf16t(v);
            a_hi[ks][j] = h;
            a_lo[ks][j] = bf16t(v - bf16tof(h));
        }
    }

    f32x4 acc[3] = {{0,0,0,0},{0,0,0,0},{0,0,0,0}};
    #pragma unroll
    for (int nt = 0; nt < 3; ++nt){
        int f = nt * 16 + r0;
        int fr = (f < 40) ? f : 39;
        const float* wp = Wc + (size_t)fr * 64 + rg * 8;
        #pragma unroll
        for (int ks = 0; ks < 2; ++ks){
            short8v b_hi, b_lo;
            #pragma unroll
            for (int j = 0; j < 8; ++j){
                float v = wp[ks * 32 + j];
                short h = bf16t(v);
                b_hi[j] = h;
                b_lo[j] = bf16t(v - bf16tof(h));
            }
            acc[nt] = __builtin_amdgcn_mfma_f32_16x16x32_bf16(a_hi[ks], b_hi, acc[nt], 0, 0, 0);
            acc[nt] = __builtin_amdgcn_mfma_f32_16x16x32_bf16(a_hi[ks], b_lo, acc[nt], 0, 0, 0);
            acc[nt] = __builtin_amdgcn_mfma_f32_16x16x32_bf16(a_lo[ks], b_hi, acc[nt], 0, 0, 0);
        }
    }

    float bcv[3];
    #pragma unroll
    for (int nt = 0; nt < 3; ++nt){
        int f = nt * 16 + r0;
        bcv[nt] = (f < 40) ? bc[f] : 0.f;
    }

    #pragma unroll
    for (int q = 0; q < 4; ++q){
        int node = nb + rg * 4 + q;
        float l0 = (r0 < 16)      ? acc[0][q] + bcv[0] : -INFINITY;  // f = r0
        float l1 = (16 + r0 < 40) ? acc[1][q] + bcv[1] : -INFINITY;  // always true
        float l2 = (32 + r0 < 40) ? acc[2][q] + bcv[2] : -INFINITY;
        float m = fmaxf(l0, fmaxf(l1, l2));
        #pragma unroll
        for (int off = 8; off; off >>= 1) m = fmaxf(m, __shfl_xor(m, off));
        float s = __expf(l0 - m) + __expf(l1 - m) + ((32 + r0 < 40) ? __expf(l2 - m) : 0.f);
        #pragma unroll
        for (int off = 8; off; off >>= 1) s += __shfl_xor(s, off);
        float lse = m + __logf(s);
        if (node < n){
            out[(size_t)node * 40 + r0]      = l0 - lse;
            out[(size_t)node * 40 + 16 + r0] = l1 - lse;
            if (32 + r0 < 40) out[(size_t)node * 40 + 32 + r0] = l2 - lse;
        }
    }
}

extern "C" void kernel_launch(void* const* d_in, const int* in_sizes, int n_in,
                              void* d_out, int out_size, void* d_ws, size_t ws_size,
                              hipStream_t stream){
    const float* x     = (const float*)d_in[0];
    const int*   ei    = (const int*)  d_in[1];
    const float* W1    = (const float*)d_in[2];
    const float* b1    = (const float*)d_in[3];
    const float* att1  = (const float*)d_in[4];
    const float* bias1 = (const float*)d_in[5];
    const float* W2    = (const float*)d_in[6];
    const float* b2    = (const float*)d_in[7];
    const float* att2  = (const float*)d_in[8];
    const float* bias2 = (const float*)d_in[9];
    const float* Wp1   = (const float*)d_in[10];
    const float* bp1   = (const float*)d_in[11];
    const float* Wp2   = (const float*)d_in[12];
    const float* bp2   = (const float*)d_in[13];
    float* out = (float*)d_out;

    // workspace carve
    float* h   = (float*)d_ws;             // [NN*64]
    float* g   = h + (size_t)NN * 64;      // [NN*64]
    float* ad  = g + (size_t)NN * 64;      // [NN]
    float* as_ = ad + NN;                  // [NN]
    int* deg      = (int*)(as_ + NN);      // [NN]
    int* rowstart = deg + NN;              // [NN+1]
    int* cursor   = rowstart + NN + 8;     // [NN]
    int* csr      = cursor + NN;           // [NE]
    float* Wc     = (float*)(csr + NE);    // [40*64]
    float* bc     = Wc + 40 * 64;          // [40]

    const int* srcv = ei;
    const int* dstv = ei + NE;

    hipMemsetAsync(deg, 0, NN * sizeof(int), stream);
    int eb = (NE + 255) / 256;
    k_hist   <<<eb, 256, 0, stream>>>(dstv, deg, NE);
    k_wcomb  <<<10, 256, 0, stream>>>(Wp1, bp1, Wp2, bp2, Wc, bc);
    k_scan   <<<1, 1024, 0, stream>>>(deg, rowstart, cursor, NN);
    k_scatter<<<eb, 256, 0, stream>>>(srcv, dstv, cursor, csr, NE);

    int gb = (NN + 63) / 64;   // 16 nodes per wave, 4 waves per block
    int nb = (NN + 3) / 4;     // 1 node per wave (k_agg)
    k_lin_mfma<<<gb, 256, 0, stream>>>(x, W1, b1, att1, h, ad, as_, NN);
    k_agg     <<<nb, 256, 0, stream>>>(h, ad, as_, rowstart, csr, bias1, g, NN);
    k_lin_mfma<<<gb, 256, 0, stream>>>(g, W2, b2, att2, h, ad, as_, NN);
    k_agg     <<<nb, 256, 0, stream>>>(h, ad, as_, rowstart, csr, bias2, g, NN);
    k_mlp_mfma<<<gb, 256, 0, stream>>>(g, Wc, bc, out, NN);
}